// Round 4
// baseline (182.293 us; speedup 1.0000x reference)
//
#include <hip/hip_runtime.h>

// Problem: B=16,C=64,H=32,W=32 -> N=16384 tokens; K=8192 codes.
#define DECAYF 0.99f
#define OMDF   0.01f
#define TAU    6.0e-3f   // >= 2*eps_screen (split ~3e-4 + drop ~2e-4 + accum ~2e-4 + pack ~5e-4), >2x margin

typedef unsigned int u32;
typedef unsigned long long u64;
typedef __attribute__((ext_vector_type(8))) short bf16x8;   // 8 bf16 (4 VGPRs)
typedef __attribute__((ext_vector_type(16))) float f32x16;  // MFMA 32x32 acc

// ws layout (bytes). High-water = 3702792 (< 5.27 MB proven).
// zfrag (4 MB, bf16 hi/lo of z_e in frag order) lives in the out0 output
// region: written by k_prep, read by k_argmin, overwritten by k_gather.
// IDX/LIST/CELL overlay EFRAG (efrag dead after k_argmin; stream-ordered).
#define EN_OFF     0              // en[8192] f32: 0.5*||e||^2
#define EFRAG_OFF  32768          // 2 MB frag-ordered bf16 hi/lo of emb (256 B/code)
#define IDX_OFF    32768          // i32 [16384] final indices       (overlay)
#define LIST_OFF   98304          // i32 [16384] ambiguous list      (overlay)
#define CELL_OFF   163840         // u64 [16384] exact-score cells   (overlay)
#define BEST1_OFF  2129920        // u64 [8][16384] per-(slice,token) best (enc)
#define BEST2_OFF  3178496        // f32 [8][16384] per-(slice,token) 2nd-best
#define CNT_OFF    3702784        // i32 count ; +4: f32 nsum (0.99*sum(cs_in))

__device__ __forceinline__ u64 enc_pair(float s, int idx) {
  u32 u = __float_as_uint(s);
  u = (u & 0x80000000u) ? ~u : (u | 0x80000000u);   // order-preserving
  return ((u64)u << 32) | (u32)(~idx);              // ~idx: ties -> min idx
}
__device__ __forceinline__ float dec_score(u64 e) {
  u32 u = (u32)(e >> 32);
  u = (u & 0x80000000u) ? (u & 0x7fffffffu) : ~u;
  return __uint_as_float(u);
}
__device__ __forceinline__ int dec_idx(u64 e) { return (int)(~(u32)e); }
__device__ __forceinline__ unsigned short f2bf(float f) {  // f32 -> bf16 RNE
  u32 u = __float_as_uint(f);
  u += 0x7fffu + ((u >> 16) & 1u);
  return (unsigned short)(u >> 16);
}
// exact f32 chain (identical FMA order to the proven full-rescan kernel)
__device__ __forceinline__ float exact_dot(const float* __restrict__ sx,
                                           const float* __restrict__ emb, int k) {
  const float4* e = (const float4*)(emb + (size_t)k * 64);
  float a = 0.f;
#pragma unroll
  for (int q = 0; q < 16; ++q) {
    float4 v = e[q];
    a = fmaf(sx[4 * q],     v.x, a);
    a = fmaf(sx[4 * q + 1], v.y, a);
    a = fmaf(sx[4 * q + 2], v.z, a);
    a = fmaf(sx[4 * q + 3], v.w, a);
  }
  return a;
}

// ---- fused prep: [0,512) eprep | [512,1032) init | [1032,2056) zprep -----
// eprep: en = 0.5*||e||^2 + emb -> bf16 hi/lo frags; cnt=0
// init : out5 = 0.99*avg (519 blocks); solo block 1031: out4 = 0.99*cs AND
//        nsum = sum (block-local reduce, no atomic -> no ordering hazard)
// zprep: z_e -> bf16 hi/lo frags in MFMA A order (dedup across slices)
__global__ __launch_bounds__(256) void k_prep(const float* __restrict__ emb,
                                              const float* __restrict__ cs_in,
                                              const float* __restrict__ avg_in,
                                              const float* __restrict__ z_e,
                                              float* __restrict__ en,
                                              unsigned char* __restrict__ efrag,
                                              unsigned char* __restrict__ zfrag,
                                              float* __restrict__ out4,
                                              float* __restrict__ out5,
                                              int* __restrict__ cnt,
                                              float* __restrict__ nsum) {
  __shared__ float warr[4];
  int bid = blockIdx.x;
  if (bid < 512) {                    // ---- eprep: 131072 float4s of emb
    int tid = bid * 256 + threadIdx.x;
    if (tid == 0) *cnt = 0;
    int k = tid >> 4, q = tid & 15;
    float4 v = ((const float4*)emb)[tid];
    int kstep = q >> 2, h = (q >> 1) & 1, j0 = (q & 1) * 4;
    int tile = k >> 5, n32 = k & 31;
    ushort4 hi, lo;
    hi.x = f2bf(v.x); lo.x = f2bf(v.x - __uint_as_float((u32)hi.x << 16));
    hi.y = f2bf(v.y); lo.y = f2bf(v.y - __uint_as_float((u32)hi.y << 16));
    hi.z = f2bf(v.z); lo.z = f2bf(v.z - __uint_as_float((u32)hi.z << 16));
    hi.w = f2bf(v.w); lo.w = f2bf(v.w - __uint_as_float((u32)hi.w << 16));
    size_t off = (size_t)tile * 8192 + (size_t)(kstep * 2) * 1024
               + (size_t)h * 512 + (size_t)n32 * 16 + (size_t)j0 * 2;
    *(ushort4*)(efrag + off)        = hi;   // split 0 (hi)
    *(ushort4*)(efrag + off + 1024) = lo;   // split 1 (lo)
    float s = v.x * v.x + v.y * v.y + v.z * v.z + v.w * v.w;
    s += __shfl_xor(s, 1, 16);
    s += __shfl_xor(s, 2, 16);
    s += __shfl_xor(s, 4, 16);
    s += __shfl_xor(s, 8, 16);
    if (q == 0) en[k] = 0.5f * s;
  } else if (bid < 1031) {            // ---- init avg: 131072 float4s
    int tid = (bid - 512) * 256 + threadIdx.x;
    if (tid < 131072) {
      float4 v = ((const float4*)avg_in)[tid];
      v.x *= DECAYF; v.y *= DECAYF; v.z *= DECAYF; v.w *= DECAYF;
      ((float4*)out5)[tid] = v;
    }
  } else if (bid == 1031) {           // ---- solo: cs scale + total sum
    int thr = threadIdx.x;
    float s = 0.f;
#pragma unroll
    for (int q = 0; q < 8; ++q) {
      int idx = q * 256 + thr;                 // 2048 float4s of cluster_size
      float4 v = ((const float4*)cs_in)[idx];
      v.x *= DECAYF; v.y *= DECAYF; v.z *= DECAYF; v.w *= DECAYF;
      ((float4*)out4)[idx] = v;
      s += v.x + v.y + v.z + v.w;              // already x0.99
    }
    s += __shfl_xor(s, 1, 64);
    s += __shfl_xor(s, 2, 64);
    s += __shfl_xor(s, 4, 64);
    s += __shfl_xor(s, 8, 64);
    s += __shfl_xor(s, 16, 64);
    s += __shfl_xor(s, 32, 64);
    if ((thr & 63) == 0) warr[thr >> 6] = s;
    __syncthreads();
    if (thr == 0) *nsum = warr[0] + warr[1] + warr[2] + warr[3];
  } else {                            // ---- zprep: 262144 float4-threads
    int t = (bid - 1032) * 256 + threadIdx.x;  // (b, c, q4): 4 tokens, 1 ch
    int q4 = t & 255, c = (t >> 8) & 63, b = t >> 14;
    size_t off = ((size_t)b << 16) + ((size_t)c << 10) + ((size_t)q4 << 2);
    float4 v = *(const float4*)(z_e + off);
    int tg = b * 32 + (q4 >> 3);               // token group (32 tokens)
    int mb = (q4 & 7) * 4;
    int ks = c >> 4, hh = (c >> 3) & 1, j = c & 7;
    size_t base = (size_t)tg * 8192 + (size_t)ks * 1024 + (size_t)hh * 512
                + (size_t)mb * 16 + (size_t)j * 2;
    float xs[4] = {v.x, v.y, v.z, v.w};
#pragma unroll
    for (int i = 0; i < 4; ++i) {
      unsigned short hi = f2bf(xs[i]);
      unsigned short lo = f2bf(xs[i] - __uint_as_float((u32)hi << 16));
      *(unsigned short*)(zfrag + base + (size_t)i * 16)        = hi;
      *(unsigned short*)(zfrag + base + (size_t)i * 16 + 4096) = lo;
    }
  }
}

// ---- MFMA argmin: 32x32x16 bf16 hi/lo 3-split; double-buffered LDS -------
// grid 1024 = 128 token-groups x 8 K-slices (1024 codes) -> 4 blk/CU exact
__global__ __launch_bounds__(256) void k_argmin_mfma(
    const unsigned char* __restrict__ zfrag,
    const unsigned char* __restrict__ efrag,
    const float* __restrict__ en, u64* __restrict__ best1,
    float* __restrict__ best2) {
  alignas(16) __shared__ unsigned char sbuf[2][16384];  // dbuf: 64 codes each
  __shared__ float sen[1024];                           // 0.5*||e||^2 slice
  const int tb = blockIdx.x >> 3;            // token group (128 tokens)
  const int sl = blockIdx.x & 7;             // K-slice (1024 codes)
  const int wave = threadIdx.x >> 6, lane = threadIdx.x & 63;
  const int h = lane >> 5, m = lane & 31;
  const int token0 = tb * 128 + wave * 32;
  const int scb = sl << 10;

  // en slice -> LDS (1024 f32 = 256 float4)
  ((float4*)sen)[threadIdx.x] = ((const float4*)(en + scb))[threadIdx.x];

  // A fragments: direct vector loads from pre-split zfrag (no conversion)
  bf16x8 ahi[4], alo[4];
  {
    const unsigned char* zb = zfrag + ((size_t)(tb * 4 + wave)) * 8192
                            + (size_t)h * 512 + (size_t)m * 16;
#pragma unroll
    for (int ks = 0; ks < 4; ++ks) {
      ahi[ks] = *(const bf16x8*)(zb + (size_t)ks * 1024);
      alo[ks] = *(const bf16x8*)(zb + (size_t)ks * 1024 + 4096);
    }
  }
  float b1[16], b2[16];
#pragma unroll
  for (int r = 0; r < 16; ++r) { b1[r] = -3.0e38f; b2[r] = -3.0e38f; }

  const unsigned char* gbase0 = efrag + (size_t)scb * 256;   // 256 B/code
  auto stage = [&](int ib, int buf) {
    const unsigned char* g = gbase0 + (size_t)ib * 16384 + (size_t)wave * 4096;
#pragma unroll
    for (int it = 0; it < 4; ++it) {
      __builtin_amdgcn_global_load_lds(
          (const __attribute__((address_space(1))) u32*)(g + it * 1024 + lane * 16),
          (__attribute__((address_space(3))) u32*)(&sbuf[buf][wave * 4096 + it * 1024]),
          16, 0, 0);
    }
  };
  stage(0, 0);                                // prologue
  for (int ib = 0; ib < 16; ++ib) {
    __syncthreads();                          // drains vmcnt -> stage(ib) done
    if (ib < 15) stage(ib + 1, (ib + 1) & 1); // prefetch overlaps compute(ib)
    const unsigned char* sb0 = &sbuf[ib & 1][0];
#pragma unroll
    for (int t32 = 0; t32 < 2; ++t32) {
      const int t = ib * 2 + t32;             // 0..31 sub-tile id in slice
      const float negen = -sen[t * 32 + m];
      f32x16 acc;
#pragma unroll
      for (int r = 0; r < 16; ++r) acc[r] = negen;   // fold -0.5||e||^2 into C
      const unsigned char* sb = sb0 + t32 * 8192 + h * 512 + m * 16;
#pragma unroll
      for (int ks = 0; ks < 4; ++ks) {
        bf16x8 bh = *(const bf16x8*)(sb + (size_t)(ks * 2 + 0) * 1024);
        bf16x8 bl = *(const bf16x8*)(sb + (size_t)(ks * 2 + 1) * 1024);
        acc = __builtin_amdgcn_mfma_f32_32x32x16_bf16(ahi[ks], bh, acc, 0, 0, 0);
        acc = __builtin_amdgcn_mfma_f32_32x32x16_bf16(alo[ks], bh, acc, 0, 0, 0);
        acc = __builtin_amdgcn_mfma_f32_32x32x16_bf16(ahi[ks], bl, acc, 0, 0, 0);
      }
      const u32 emb6 = (u32)(63 - t);         // sub-idx in low 6 mantissa bits
#pragma unroll
      for (int r = 0; r < 16; ++r) {
        float f = __uint_as_float((__float_as_uint(acc[r]) & 0xFFFFFFC0u) | emb6);
        b2[r] = __builtin_amdgcn_fmed3f(f, b1[r], b2[r]);         // v_med3
        b1[r] = fmaxf(b1[r], f);                                  // v_max
      }
    }
  }
  int mi[16];
#pragma unroll
  for (int r = 0; r < 16; ++r) mi[r] = m;
#pragma unroll
  for (int st = 1; st < 32; st <<= 1) {
#pragma unroll
    for (int r = 0; r < 16; ++r) {
      float ob1 = __shfl_xor(b1[r], st, 64);
      float ob2 = __shfl_xor(b2[r], st, 64);
      int omi = __shfl_xor(mi[r], st, 64);
      bool ogt = ob1 > b1[r];            // strict: equal -> quantized tie -> fixup
      b2[r] = fmaxf(fminf(b1[r], ob1), fmaxf(b2[r], ob2));
      mi[r] = ogt ? omi : mi[r];
      b1[r] = fmaxf(b1[r], ob1);
    }
  }
  if (m == 0) {     // lanes 0 and 32: 16 token-rows each; [sl][token] layout
#pragma unroll
    for (int r = 0; r < 16; ++r) {
      int row = (r & 3) + 8 * (r >> 2) + 4 * h;   // C/D row map [m74/m101]
      int token = token0 + row;
      int t = 63 - (int)(__float_as_uint(b1[r]) & 63u);
      int gcode = scb + t * 32 + mi[r];
      best1[(size_t)sl * 16384 + token] = enc_pair(b1[r], gcode);
      best2[(size_t)sl * 16384 + token] = b2[r];
    }
  }
}

// ---- merge slices, pick top1, flag ambiguous tokens ---------------------
__global__ __launch_bounds__(256) void k_resolve(const u64* __restrict__ best1,
                                                 const float* __restrict__ best2,
                                                 int* __restrict__ idxa,
                                                 int* __restrict__ list,
                                                 int* __restrict__ cnt) {
  int n = blockIdx.x * 256 + threadIdx.x;   // 16384
  u64 e[8];
  float sp[8];
#pragma unroll
  for (int s = 0; s < 8; ++s) {
    e[s]  = best1[(size_t)s * 16384 + n];
    sp[s] = best2[(size_t)s * 16384 + n];
  }
  u64 top = e[0];
#pragma unroll
  for (int s = 1; s < 8; ++s) top = e[s] > top ? e[s] : top;
  float second = -3.0e38f;
#pragma unroll
  for (int s = 0; s < 8; ++s) second = fmaxf(second, sp[s]);
#pragma unroll
  for (int s = 0; s < 8; ++s)
    if (e[s] != top) second = fmaxf(second, dec_score(e[s]));
  idxa[n] = dec_idx(top);
  if (dec_score(top) - second < TAU) {
    int p = atomicAdd(cnt, 1);
    list[p] = n;
  }
}

// ---- candidate-based exact fp32 fixup: one block per flagged token ------
// Candidates: per-slice best with screened >= theta; slices whose 2nd-best
// >= theta (rare) get a full 1024-code exact rescan. theta = top - TAU.
// Rigor: |exact - screened| <= eps, TAU >= 2*eps  =>  true argmin is in set.
__global__ __launch_bounds__(256) void k_fixup(const float* __restrict__ z_e,
                                               const float* __restrict__ emb,
                                               const float* __restrict__ en,
                                               const u64* __restrict__ best1,
                                               const float* __restrict__ best2,
                                               const int* __restrict__ list,
                                               const int* __restrict__ cnt,
                                               u64* __restrict__ cell) {
  __shared__ float sx[64];
  __shared__ u64 esh[8];
  __shared__ float b2sh[8];
  __shared__ int cand[8];
  __shared__ int fsl[8];
  __shared__ int ncand, nfsl;
  __shared__ u64 red;
  int count = *cnt;
  for (int i = blockIdx.x; i < count; i += gridDim.x) {
    int n = list[i];
    __syncthreads();                       // protect prev-iter LDS
    if (threadIdx.x == 0) { ncand = 0; nfsl = 0; red = 0ull; }
    if (threadIdx.x < 8) {
      esh[threadIdx.x]  = best1[(size_t)threadIdx.x * 16384 + n];
      b2sh[threadIdx.x] = best2[(size_t)threadIdx.x * 16384 + n];
    }
    if (threadIdx.x < 64) {
      sx[threadIdx.x] = z_e[((size_t)(n >> 10) << 16)
                            + ((size_t)threadIdx.x << 10) + (n & 1023)];
    }
    __syncthreads();
    u64 top = esh[0];
#pragma unroll
    for (int s = 1; s < 8; ++s) top = esh[s] > top ? esh[s] : top;
    float theta = dec_score(top) - TAU;
    if (threadIdx.x < 8) {
      int s = threadIdx.x;
      if (dec_score(esh[s]) >= theta) {
        int p = atomicAdd(&ncand, 1);
        cand[p] = dec_idx(esh[s]);
      }
      if (b2sh[s] >= theta) {
        int p = atomicAdd(&nfsl, 1);
        fsl[p] = s;
      }
    }
    __syncthreads();
    u64 myb = 0ull;
    if (threadIdx.x < ncand) {             // phase 1: <=8 candidate codes
      int k = cand[threadIdx.x];
      float a = exact_dot(sx, emb, k) - en[k];
      myb = enc_pair(a, k);
    }
    int nf = nfsl;
    for (int f = 0; f < nf; ++f) {         // phase 2: rare full-slice rescan
      int s = fsl[f];
      int k0 = (s << 10) + threadIdx.x;    // 4 codes: +0,+256,+512,+768
      float a0 = exact_dot(sx, emb, k0)       - en[k0];
      float a1 = exact_dot(sx, emb, k0 + 256) - en[k0 + 256];
      float a2 = exact_dot(sx, emb, k0 + 512) - en[k0 + 512];
      float a3 = exact_dot(sx, emb, k0 + 768) - en[k0 + 768];
      u64 m0 = enc_pair(a0, k0),       m1 = enc_pair(a1, k0 + 256);
      u64 m2 = enc_pair(a2, k0 + 512), m3 = enc_pair(a3, k0 + 768);
      u64 ma = m0 > m1 ? m0 : m1, mb = m2 > m3 ? m2 : m3;
      u64 mm = ma > mb ? ma : mb;
      myb = mm > myb ? mm : myb;
    }
    if (myb) atomicMax(&red, myb);
    __syncthreads();
    if (threadIdx.x == 0) cell[i] = red;
  }
}

// ---- write back fixed indices -------------------------------------------
__global__ __launch_bounds__(256) void k_post(const int* __restrict__ list,
                                              const int* __restrict__ cnt,
                                              const u64* __restrict__ cell,
                                              int* __restrict__ idxa) {
  int i = blockIdx.x * 256 + threadIdx.x;
  if (i < *cnt) idxa[list[i]] = dec_idx(cell[i]);
}

// ---- scatter EMA stats (lane = channel -> coalesced atomics) -------------
__global__ __launch_bounds__(256) void k_scatter(const float* __restrict__ z_e,
                                                 const int* __restrict__ idxa,
                                                 float* __restrict__ out4,
                                                 float* __restrict__ out5) {
  int tid = blockIdx.x * 256 + threadIdx.x;   // 1M = 16384 tokens x 64 ch
  int n = tid >> 6, c = tid & 63;
  int idx = idxa[n];
  int b = n >> 10, hw = n & 1023;
  float x = z_e[((size_t)b << 16) + ((size_t)c << 10) + hw];
  atomicAdd(out5 + (size_t)idx * 64 + c, OMDF * x);
  if (c == 0) atomicAdd(out4 + idx, OMDF);
}

// ---- gather z_q / z_q_st / indices --------------------------------------
__global__ __launch_bounds__(256) void k_gather(const float* __restrict__ z_e,
                                                const float* __restrict__ emb,
                                                const int* __restrict__ idxa,
                                                float* __restrict__ out0,
                                                float* __restrict__ out1,
                                                float* __restrict__ out2) {
  int tid = blockIdx.x * 256 + threadIdx.x;   // 262144 = 16 b x 64 c x 256 hw4
  int hw4 = tid & 255;
  int c   = (tid >> 8) & 63;
  int b   = tid >> 14;
  int n0  = (b << 10) + (hw4 << 2);
  size_t off = ((size_t)b << 16) + ((size_t)c << 10) + ((size_t)hw4 << 2);
  float4 z = *(const float4*)(z_e + off);
  int i0 = idxa[n0], i1 = idxa[n0 + 1], i2 = idxa[n0 + 2], i3 = idxa[n0 + 3];
  float4 q;
  q.x = emb[(size_t)i0 * 64 + c];
  q.y = emb[(size_t)i1 * 64 + c];
  q.z = emb[(size_t)i2 * 64 + c];
  q.w = emb[(size_t)i3 * 64 + c];
  float4 st;
  st.x = z.x + (q.x - z.x);
  st.y = z.y + (q.y - z.y);
  st.z = z.z + (q.z - z.z);
  st.w = z.w + (q.w - z.w);
  *(float4*)(out2 + off) = q;
  *(float4*)(out0 + off) = st;
  if (c == 0) {
    float4 f = make_float4((float)i0, (float)i1, (float)i2, (float)i3);
    *(float4*)(out1 + n0) = f;
  }
}

// ---- new_embedding = new_embedding_avg / cs -----------------------------
__global__ __launch_bounds__(256) void k_final(const float* __restrict__ out4,
                                               const float* __restrict__ out5,
                                               const float* __restrict__ nsum,
                                               float* __restrict__ out3) {
  int tid = blockIdx.x * 256 + threadIdx.x;
  int k = tid >> 4;
  double nn  = (double)*nsum + 163.84;
  double ncs = (double)out4[k];
  double cs  = (ncs + 1e-5) / (nn + 8192.0 * 1e-5) * nn;
  float inv  = (float)(1.0 / cs);
  float4 v = ((const float4*)out5)[tid];
  v.x *= inv; v.y *= inv; v.z *= inv; v.w *= inv;
  ((float4*)out3)[tid] = v;
}

extern "C" void kernel_launch(void* const* d_in, const int* in_sizes, int n_in,
                              void* d_out, int out_size, void* d_ws, size_t ws_size,
                              hipStream_t stream) {
  const float* z_e    = (const float*)d_in[0];
  const float* emb    = (const float*)d_in[1];
  const float* cs_in  = (const float*)d_in[2];
  const float* avg_in = (const float*)d_in[3];

  float* out  = (float*)d_out;
  float* out0 = out;                    // z_q_st        1048576
  float* out1 = out0 + 1048576;         // indices(f32)  16384
  float* out2 = out1 + 16384;           // z_q           1048576
  float* out3 = out2 + 1048576;         // new_embedding 524288
  float* out4 = out3 + 524288;          // new_cluster   8192
  float* out5 = out4 + 8192;            // new_emb_avg   524288

  char* ws = (char*)d_ws;
  float* en            = (float*)(ws + EN_OFF);
  unsigned char* efrag = (unsigned char*)(ws + EFRAG_OFF);
  u64* best1           = (u64*)(ws + BEST1_OFF);
  float* best2         = (float*)(ws + BEST2_OFF);
  int* idxa            = (int*)(ws + IDX_OFF);
  int* list            = (int*)(ws + LIST_OFF);
  int* cnt             = (int*)(ws + CNT_OFF);
  float* nsum          = (float*)(ws + CNT_OFF + 4);
  u64* cell            = (u64*)(ws + CELL_OFF);
  unsigned char* zfrag = (unsigned char*)out0;   // 4 MB scratch in out0 region

  k_prep       <<<2056, 256, 0, stream>>>(emb, cs_in, avg_in, z_e, en, efrag,
                                          zfrag, out4, out5, cnt, nsum);
  k_argmin_mfma<<<1024, 256, 0, stream>>>(zfrag, efrag, en, best1, best2);
  k_resolve    <<<64,   256, 0, stream>>>(best1, best2, idxa, list, cnt);
  k_fixup      <<<1024, 256, 0, stream>>>(z_e, emb, en, best1, best2, list, cnt, cell);
  k_post       <<<64,   256, 0, stream>>>(list, cnt, cell, idxa);
  k_scatter    <<<4096, 256, 0, stream>>>(z_e, idxa, out4, out5);
  k_gather     <<<1024, 256, 0, stream>>>(z_e, emb, idxa, out0, out1, out2);
  k_final      <<<512,  256, 0, stream>>>(out4, out5, nsum, out3);
}

// Round 6
// 158.201 us; speedup vs baseline: 1.1523x; 1.1523x over previous
//
#include <hip/hip_runtime.h>

// Problem: B=16,C=64,H=32,W=32 -> N=16384 tokens; K=8192 codes.
#define DECAYF 0.99f
#define OMDF   0.01f
#define TAU    3.5e-2f   // fp16 screen: ~9-sigma pairwise (sigma~3.8e-3); candidate fixup exact f32

typedef unsigned int u32;
typedef unsigned long long u64;
typedef __attribute__((ext_vector_type(8))) _Float16 f16x8;  // 8 fp16 (4 VGPRs)
typedef __attribute__((ext_vector_type(16))) float f32x16;   // MFMA 32x32 acc

// ws layout (bytes). High-water = 3702792.
// zfrag (2 MB, fp16 z_e in frag order) lives in the out0 output region:
// written by k_prep, read by k_argmin, overwritten by k_gather (stream-ordered).
// IDX/LIST overlay EFRAG (efrag dead after k_argmin; stream-ordered).
#define EN_OFF     0              // en[8192] f32: 0.5*||e||^2
#define EFRAG_OFF  32768          // 2 MB frag-ordered fp16 emb (128 B/code)
#define IDX_OFF    32768          // i32 [16384] final indices       (overlay)
#define LIST_OFF   98304          // i32 [16384] ambiguous list      (overlay)
#define BEST1_OFF  2129920        // u64 [8][16384] per-(slice,token) best (enc)
#define BEST2_OFF  3178496        // f32 [8][16384] per-(slice,token) 2nd-best
#define CNT_OFF    3702784        // i32 count ; +4: f32 nsum (0.99*sum(cs_in))

__device__ __forceinline__ u64 enc_pair(float s, int idx) {
  u32 u = __float_as_uint(s);
  u = (u & 0x80000000u) ? ~u : (u | 0x80000000u);   // order-preserving
  return ((u64)u << 32) | (u32)(~idx);              // ~idx: ties -> min idx
}
__device__ __forceinline__ float dec_score(u64 e) {
  u32 u = (u32)(e >> 32);
  u = (u & 0x80000000u) ? (u & 0x7fffffffu) : ~u;
  return __uint_as_float(u);
}
__device__ __forceinline__ int dec_idx(u64 e) { return (int)(~(u32)e); }
__device__ __forceinline__ unsigned short f2h(float f) {  // f32 -> fp16 RNE
  union { _Float16 h; unsigned short u; } v;
  v.h = (_Float16)f;
  return v.u;
}
// exact f32 chain (identical FMA order across screen/fixup uses)
__device__ __forceinline__ float exact_dot(const float* __restrict__ sx,
                                           const float* __restrict__ emb, int k) {
  const float4* e = (const float4*)(emb + (size_t)k * 64);
  float a = 0.f;
#pragma unroll
  for (int q = 0; q < 16; ++q) {
    float4 v = e[q];
    a = fmaf(sx[4 * q],     v.x, a);
    a = fmaf(sx[4 * q + 1], v.y, a);
    a = fmaf(sx[4 * q + 2], v.z, a);
    a = fmaf(sx[4 * q + 3], v.w, a);
  }
  return a;
}

// ---- fused prep: [0,512) eprep | [512,1032) init | [1032,1544) zprep -----
// eprep: en = 0.5*||e||^2 + emb -> fp16 frags; cnt=0
// init : out5 = 0.99*avg (519 blocks); solo block 1031: out4 = 0.99*cs AND
//        nsum = sum (block-local reduce, no atomic)
// zprep: z_e -> fp16 frags in MFMA A order; contiguous 16-B stores per lane
__global__ __launch_bounds__(256) void k_prep(const float* __restrict__ emb,
                                              const float* __restrict__ cs_in,
                                              const float* __restrict__ avg_in,
                                              const float* __restrict__ z_e,
                                              float* __restrict__ en,
                                              unsigned char* __restrict__ efrag,
                                              unsigned char* __restrict__ zfrag,
                                              float* __restrict__ out4,
                                              float* __restrict__ out5,
                                              int* __restrict__ cnt,
                                              float* __restrict__ nsum) {
  __shared__ float warr[4];
  int bid = blockIdx.x;
  if (bid < 512) {                    // ---- eprep: 131072 float4s of emb
    int tid = bid * 256 + threadIdx.x;
    if (tid == 0) *cnt = 0;
    int k = tid >> 4, q = tid & 15;
    float4 v = ((const float4*)emb)[tid];
    int kstep = q >> 2, h = (q >> 1) & 1, j0 = (q & 1) * 4;
    int tile = k >> 5, n32 = k & 31;
    ushort4 hv;
    hv.x = f2h(v.x); hv.y = f2h(v.y); hv.z = f2h(v.z); hv.w = f2h(v.w);
    size_t off = (size_t)tile * 4096 + (size_t)kstep * 1024
               + (size_t)h * 512 + (size_t)n32 * 16 + (size_t)j0 * 2;
    *(ushort4*)(efrag + off) = hv;
    float s = v.x * v.x + v.y * v.y + v.z * v.z + v.w * v.w;
    s += __shfl_xor(s, 1, 16);
    s += __shfl_xor(s, 2, 16);
    s += __shfl_xor(s, 4, 16);
    s += __shfl_xor(s, 8, 16);
    if (q == 0) en[k] = 0.5f * s;
  } else if (bid < 1031) {            // ---- init avg: 131072 float4s
    int tid = (bid - 512) * 256 + threadIdx.x;
    if (tid < 131072) {
      float4 v = ((const float4*)avg_in)[tid];
      v.x *= DECAYF; v.y *= DECAYF; v.z *= DECAYF; v.w *= DECAYF;
      ((float4*)out5)[tid] = v;
    }
  } else if (bid == 1031) {           // ---- solo: cs scale + total sum
    int thr = threadIdx.x;
    float s = 0.f;
#pragma unroll
    for (int q = 0; q < 8; ++q) {
      int idx = q * 256 + thr;                 // 2048 float4s of cluster_size
      float4 v = ((const float4*)cs_in)[idx];
      v.x *= DECAYF; v.y *= DECAYF; v.z *= DECAYF; v.w *= DECAYF;
      ((float4*)out4)[idx] = v;
      s += v.x + v.y + v.z + v.w;              // already x0.99
    }
    s += __shfl_xor(s, 1, 64);
    s += __shfl_xor(s, 2, 64);
    s += __shfl_xor(s, 4, 64);
    s += __shfl_xor(s, 8, 64);
    s += __shfl_xor(s, 16, 64);
    s += __shfl_xor(s, 32, 64);
    if ((thr & 63) == 0) warr[thr >> 6] = s;
    __syncthreads();
    if (thr == 0) *nsum = warr[0] + warr[1] + warr[2] + warr[3];
  } else {                            // ---- zprep: 131072 threads
    int t = (bid - 1032) * 256 + threadIdx.x;  // (tg, ks, h, m)
    int m = t & 31, h = (t >> 5) & 1, ks = (t >> 6) & 3, tg = t >> 8;
    int token = tg * 32 + m;
    int b = token >> 10, hw = token & 1023;
    const float* zr = z_e + ((size_t)b << 16) + hw;
    int c0 = ks * 16 + h * 8;
    unsigned short u[8];
#pragma unroll
    for (int j = 0; j < 8; ++j) u[j] = f2h(zr[(size_t)(c0 + j) << 10]);
    size_t off = (size_t)tg * 4096 + (size_t)ks * 1024
               + (size_t)h * 512 + (size_t)m * 16;
    ((ushort4*)(zfrag + off))[0] = make_ushort4(u[0], u[1], u[2], u[3]);
    ((ushort4*)(zfrag + off))[1] = make_ushort4(u[4], u[5], u[6], u[7]);
  }
}

// ---- MFMA argmin: 32x32x16 fp16 single; double-buffered LDS --------------
// grid 1024 = 128 token-groups x 8 K-slices (1024 codes) -> 4 blk/CU
__global__ __launch_bounds__(256) void k_argmin_mfma(
    const unsigned char* __restrict__ zfrag,
    const unsigned char* __restrict__ efrag,
    const float* __restrict__ en, u64* __restrict__ best1,
    float* __restrict__ best2) {
  alignas(16) __shared__ unsigned char sbuf[2][8192];   // dbuf: 64 codes each
  __shared__ float sen[1024];                           // 0.5*||e||^2 slice
  const int tb = blockIdx.x >> 3;            // token group (128 tokens)
  const int sl = blockIdx.x & 7;             // K-slice (1024 codes)
  const int wave = threadIdx.x >> 6, lane = threadIdx.x & 63;
  const int h = lane >> 5, m = lane & 31;
  const int token0 = tb * 128 + wave * 32;
  const int scb = sl << 10;

  // en slice -> LDS (1024 f32 = 256 float4)
  ((float4*)sen)[threadIdx.x] = ((const float4*)(en + scb))[threadIdx.x];

  // A fragments: direct vector loads from pre-split zfrag
  f16x8 a[4];
  {
    const unsigned char* zb = zfrag + ((size_t)(tb * 4 + wave)) * 4096
                            + (size_t)h * 512 + (size_t)m * 16;
#pragma unroll
    for (int ks = 0; ks < 4; ++ks) a[ks] = *(const f16x8*)(zb + (size_t)ks * 1024);
  }
  float b1[16], b2[16];
#pragma unroll
  for (int r = 0; r < 16; ++r) { b1[r] = -3.0e38f; b2[r] = -3.0e38f; }

  const unsigned char* gbase0 = efrag + (size_t)scb * 128;   // 128 B/code
  auto stage = [&](int ib, int buf) {
    const unsigned char* g = gbase0 + (size_t)ib * 8192 + (size_t)wave * 2048;
#pragma unroll
    for (int it = 0; it < 2; ++it) {
      __builtin_amdgcn_global_load_lds(
          (const __attribute__((address_space(1))) u32*)(g + it * 1024 + lane * 16),
          (__attribute__((address_space(3))) u32*)(&sbuf[buf][wave * 2048 + it * 1024]),
          16, 0, 0);
    }
  };
  stage(0, 0);                                // prologue
  for (int ib = 0; ib < 16; ++ib) {
    __syncthreads();                          // drains vmcnt -> stage(ib) done
    if (ib < 15) stage(ib + 1, (ib + 1) & 1); // prefetch overlaps compute(ib)
    const unsigned char* sb0 = &sbuf[ib & 1][0];
#pragma unroll
    for (int t32 = 0; t32 < 2; ++t32) {
      const int t = ib * 2 + t32;             // 0..31 sub-tile id in slice
      const float negen = -sen[t * 32 + m];
      f32x16 acc;
#pragma unroll
      for (int r = 0; r < 16; ++r) acc[r] = negen;   // fold -0.5||e||^2 into C
      const unsigned char* sb = sb0 + t32 * 4096 + h * 512 + m * 16;
#pragma unroll
      for (int ks = 0; ks < 4; ++ks) {
        f16x8 bf = *(const f16x8*)(sb + (size_t)ks * 1024);
        acc = __builtin_amdgcn_mfma_f32_32x32x16_f16(a[ks], bf, acc, 0, 0, 0);
      }
      const u32 emb6 = (u32)(63 - t);         // sub-idx in low 6 mantissa bits
#pragma unroll
      for (int r = 0; r < 16; ++r) {
        float f = __uint_as_float((__float_as_uint(acc[r]) & 0xFFFFFFC0u) | emb6);
        b2[r] = __builtin_amdgcn_fmed3f(f, b1[r], b2[r]);         // v_med3
        b1[r] = fmaxf(b1[r], f);                                  // v_max
      }
    }
  }
  int mi[16];
#pragma unroll
  for (int r = 0; r < 16; ++r) mi[r] = m;
#pragma unroll
  for (int st = 1; st < 32; st <<= 1) {
#pragma unroll
    for (int r = 0; r < 16; ++r) {
      float ob1 = __shfl_xor(b1[r], st, 64);
      float ob2 = __shfl_xor(b2[r], st, 64);
      int omi = __shfl_xor(mi[r], st, 64);
      bool ogt = ob1 > b1[r];            // strict: equal -> quantized tie -> fixup
      b2[r] = fmaxf(fminf(b1[r], ob1), fmaxf(b2[r], ob2));
      mi[r] = ogt ? omi : mi[r];
      b1[r] = fmaxf(b1[r], ob1);
    }
  }
  if (m == 0) {     // lanes 0 and 32: 16 token-rows each; [sl][token] layout
#pragma unroll
    for (int r = 0; r < 16; ++r) {
      int row = (r & 3) + 8 * (r >> 2) + 4 * h;   // C/D row map [m74/m101]
      int token = token0 + row;
      int t = 63 - (int)(__float_as_uint(b1[r]) & 63u);
      int gcode = scb + t * 32 + mi[r];
      best1[(size_t)sl * 16384 + token] = enc_pair(b1[r], gcode);
      best2[(size_t)sl * 16384 + token] = b2[r];
    }
  }
}

// ---- merge slices, pick top1, flag ambiguous tokens ---------------------
__global__ __launch_bounds__(256) void k_resolve(const u64* __restrict__ best1,
                                                 const float* __restrict__ best2,
                                                 int* __restrict__ idxa,
                                                 int* __restrict__ list,
                                                 int* __restrict__ cnt) {
  int n = blockIdx.x * 256 + threadIdx.x;   // 16384
  u64 e[8];
  float sp[8];
#pragma unroll
  for (int s = 0; s < 8; ++s) {
    e[s]  = best1[(size_t)s * 16384 + n];
    sp[s] = best2[(size_t)s * 16384 + n];
  }
  u64 top = e[0];
#pragma unroll
  for (int s = 1; s < 8; ++s) top = e[s] > top ? e[s] : top;
  float second = -3.0e38f;
#pragma unroll
  for (int s = 0; s < 8; ++s) second = fmaxf(second, sp[s]);
#pragma unroll
  for (int s = 0; s < 8; ++s)
    if (e[s] != top) second = fmaxf(second, dec_score(e[s]));
  idxa[n] = dec_idx(top);
  if (dec_score(top) - second < TAU) {
    int p = atomicAdd(cnt, 1);
    list[p] = n;
  }
}

// ---- candidate-based exact fp32 fixup: one block per flagged token ------
// Candidates: per-slice best with screened >= theta; slices whose 2nd-best
// >= theta get a full 1024-code exact rescan. theta = top - TAU.
// Rigor: |exact - screened| <= eps, TAU >= 2*eps  =>  true argmin in set.
// Writes idxa directly (block owns the token).
__global__ __launch_bounds__(256) void k_fixup(const float* __restrict__ z_e,
                                               const float* __restrict__ emb,
                                               const float* __restrict__ en,
                                               const u64* __restrict__ best1,
                                               const float* __restrict__ best2,
                                               const int* __restrict__ list,
                                               const int* __restrict__ cnt,
                                               int* __restrict__ idxa) {
  __shared__ float sx[64];
  __shared__ u64 esh[8];
  __shared__ float b2sh[8];
  __shared__ int cand[8];
  __shared__ int fsl[8];
  __shared__ int ncand, nfsl;
  __shared__ u64 red;
  int count = *cnt;
  for (int i = blockIdx.x; i < count; i += gridDim.x) {
    int n = list[i];
    __syncthreads();                       // protect prev-iter LDS
    if (threadIdx.x == 0) { ncand = 0; nfsl = 0; red = 0ull; }
    if (threadIdx.x < 8) {
      esh[threadIdx.x]  = best1[(size_t)threadIdx.x * 16384 + n];
      b2sh[threadIdx.x] = best2[(size_t)threadIdx.x * 16384 + n];
    }
    if (threadIdx.x < 64) {
      sx[threadIdx.x] = z_e[((size_t)(n >> 10) << 16)
                            + ((size_t)threadIdx.x << 10) + (n & 1023)];
    }
    __syncthreads();
    u64 top = esh[0];
#pragma unroll
    for (int s = 1; s < 8; ++s) top = esh[s] > top ? esh[s] : top;
    float theta = dec_score(top) - TAU;
    if (threadIdx.x < 8) {
      int s = threadIdx.x;
      if (dec_score(esh[s]) >= theta) {
        int p = atomicAdd(&ncand, 1);
        cand[p] = dec_idx(esh[s]);
      }
      if (b2sh[s] >= theta) {
        int p = atomicAdd(&nfsl, 1);
        fsl[p] = s;
      }
    }
    __syncthreads();
    u64 myb = 0ull;
    if (threadIdx.x < ncand) {             // phase 1: <=8 candidate codes
      int k = cand[threadIdx.x];
      float a = exact_dot(sx, emb, k) - en[k];
      myb = enc_pair(a, k);
    }
    int nf = nfsl;
    for (int f = 0; f < nf; ++f) {         // phase 2: rare full-slice rescan
      int s = fsl[f];
      int k0 = (s << 10) + threadIdx.x;    // 4 codes: +0,+256,+512,+768
      float a0 = exact_dot(sx, emb, k0)       - en[k0];
      float a1 = exact_dot(sx, emb, k0 + 256) - en[k0 + 256];
      float a2 = exact_dot(sx, emb, k0 + 512) - en[k0 + 512];
      float a3 = exact_dot(sx, emb, k0 + 768) - en[k0 + 768];
      u64 m0 = enc_pair(a0, k0),       m1 = enc_pair(a1, k0 + 256);
      u64 m2 = enc_pair(a2, k0 + 512), m3 = enc_pair(a3, k0 + 768);
      u64 ma = m0 > m1 ? m0 : m1, mb = m2 > m3 ? m2 : m3;
      u64 mm = ma > mb ? ma : mb;
      myb = mm > myb ? mm : myb;
    }
    if (myb) atomicMax(&red, myb);
    __syncthreads();
    if (threadIdx.x == 0) idxa[n] = dec_idx(red);
  }
}

// ---- scatter EMA stats (lane = channel -> coalesced atomics) -------------
__global__ __launch_bounds__(256) void k_scatter(const float* __restrict__ z_e,
                                                 const int* __restrict__ idxa,
                                                 float* __restrict__ out4,
                                                 float* __restrict__ out5) {
  int tid = blockIdx.x * 256 + threadIdx.x;   // 1M = 16384 tokens x 64 ch
  int n = tid >> 6, c = tid & 63;
  int idx = idxa[n];
  int b = n >> 10, hw = n & 1023;
  float x = z_e[((size_t)b << 16) + ((size_t)c << 10) + hw];
  atomicAdd(out5 + (size_t)idx * 64 + c, OMDF * x);
  if (c == 0) atomicAdd(out4 + idx, OMDF);
}

// ---- gather z_q / z_q_st / indices --------------------------------------
__global__ __launch_bounds__(256) void k_gather(const float* __restrict__ z_e,
                                                const float* __restrict__ emb,
                                                const int* __restrict__ idxa,
                                                float* __restrict__ out0,
                                                float* __restrict__ out1,
                                                float* __restrict__ out2) {
  int tid = blockIdx.x * 256 + threadIdx.x;   // 262144 = 16 b x 64 c x 256 hw4
  int hw4 = tid & 255;
  int c   = (tid >> 8) & 63;
  int b   = tid >> 14;
  int n0  = (b << 10) + (hw4 << 2);
  size_t off = ((size_t)b << 16) + ((size_t)c << 10) + ((size_t)hw4 << 2);
  float4 z = *(const float4*)(z_e + off);
  int i0 = idxa[n0], i1 = idxa[n0 + 1], i2 = idxa[n0 + 2], i3 = idxa[n0 + 3];
  float4 q;
  q.x = emb[(size_t)i0 * 64 + c];
  q.y = emb[(size_t)i1 * 64 + c];
  q.z = emb[(size_t)i2 * 64 + c];
  q.w = emb[(size_t)i3 * 64 + c];
  float4 st;
  st.x = z.x + (q.x - z.x);
  st.y = z.y + (q.y - z.y);
  st.z = z.z + (q.z - z.z);
  st.w = z.w + (q.w - z.w);
  *(float4*)(out2 + off) = q;
  *(float4*)(out0 + off) = st;
  if (c == 0) {
    float4 f = make_float4((float)i0, (float)i1, (float)i2, (float)i3);
    *(float4*)(out1 + n0) = f;
  }
}

// ---- new_embedding = new_embedding_avg / cs -----------------------------
__global__ __launch_bounds__(256) void k_final(const float* __restrict__ out4,
                                               const float* __restrict__ out5,
                                               const float* __restrict__ nsum,
                                               float* __restrict__ out3) {
  int tid = blockIdx.x * 256 + threadIdx.x;
  int k = tid >> 4;
  double nn  = (double)*nsum + 163.84;
  double ncs = (double)out4[k];
  double cs  = (ncs + 1e-5) / (nn + 8192.0 * 1e-5) * nn;
  float inv  = (float)(1.0 / cs);
  float4 v = ((const float4*)out5)[tid];
  v.x *= inv; v.y *= inv; v.z *= inv; v.w *= inv;
  ((float4*)out3)[tid] = v;
}

extern "C" void kernel_launch(void* const* d_in, const int* in_sizes, int n_in,
                              void* d_out, int out_size, void* d_ws, size_t ws_size,
                              hipStream_t stream) {
  const float* z_e    = (const float*)d_in[0];
  const float* emb    = (const float*)d_in[1];
  const float* cs_in  = (const float*)d_in[2];
  const float* avg_in = (const float*)d_in[3];

  float* out  = (float*)d_out;
  float* out0 = out;                    // z_q_st        1048576
  float* out1 = out0 + 1048576;         // indices(f32)  16384
  float* out2 = out1 + 16384;           // z_q           1048576
  float* out3 = out2 + 1048576;         // new_embedding 524288
  float* out4 = out3 + 524288;          // new_cluster   8192
  float* out5 = out4 + 8192;            // new_emb_avg   524288

  char* ws = (char*)d_ws;
  float* en            = (float*)(ws + EN_OFF);
  unsigned char* efrag = (unsigned char*)(ws + EFRAG_OFF);
  u64* best1           = (u64*)(ws + BEST1_OFF);
  float* best2         = (float*)(ws + BEST2_OFF);
  int* idxa            = (int*)(ws + IDX_OFF);
  int* list            = (int*)(ws + LIST_OFF);
  int* cnt             = (int*)(ws + CNT_OFF);
  float* nsum          = (float*)(ws + CNT_OFF + 4);
  unsigned char* zfrag = (unsigned char*)out0;   // 2 MB scratch in out0 region

  k_prep       <<<1544, 256, 0, stream>>>(emb, cs_in, avg_in, z_e, en, efrag,
                                          zfrag, out4, out5, cnt, nsum);
  k_argmin_mfma<<<1024, 256, 0, stream>>>(zfrag, efrag, en, best1, best2);
  k_resolve    <<<64,   256, 0, stream>>>(best1, best2, idxa, list, cnt);
  k_fixup      <<<1024, 256, 0, stream>>>(z_e, emb, en, best1, best2, list, cnt, idxa);
  k_scatter    <<<4096, 256, 0, stream>>>(z_e, idxa, out4, out5);
  k_gather     <<<1024, 256, 0, stream>>>(z_e, emb, idxa, out0, out1, out2);
  k_final      <<<512,  256, 0, stream>>>(out4, out5, nsum, out3);
}

// Round 7
// 148.899 us; speedup vs baseline: 1.2243x; 1.0625x over previous
//
#include <hip/hip_runtime.h>

// Problem: B=16,C=64,H=32,W=32 -> N=16384 tokens; K=8192 codes.
#define DECAYF 0.99f
#define OMDF   0.01f
#define TAU    3.5e-2f   // fp16 screen: ~9-sigma pairwise (sigma~3.8e-3); candidate fixup exact f32

typedef unsigned int u32;
typedef unsigned long long u64;
typedef __attribute__((ext_vector_type(8))) _Float16 f16x8;  // 8 fp16 (4 VGPRs)
typedef __attribute__((ext_vector_type(4))) float f32x4;     // MFMA 16x16 acc

// ws layout (bytes). High-water = 3702792.
// zfrag (2 MB, fp16 z_e in 16x16 A-frag order) lives in the out0 output
// region: written by k_prep, read by k_argmin, overwritten by k_gather.
// IDX/LIST overlay EFRAG (efrag dead after k_argmin; stream-ordered).
// efrag: 512 tiles x 2048 B. Tile (16 codes): [frag0 1KB][frag1 1KB], each
// laid out lane*16 with cell (kblk=lane>>4, code=lane&15) = 8 contiguous ch.
#define EN_OFF     0              // en[8192] f32: 0.5*||e||^2
#define EFRAG_OFF  32768          // 1 MB frag-ordered fp16 emb (128 B/code)
#define IDX_OFF    32768          // i32 [16384] final indices       (overlay)
#define LIST_OFF   98304          // i32 [16384] ambiguous list      (overlay)
#define BEST1_OFF  2129920        // u64 [8][16384] per-(slice,token) best (enc)
#define BEST2_OFF  3178496        // f32 [8][16384] per-(slice,token) 2nd-best
#define CNT_OFF    3702784        // i32 count ; +4: f32 nsum (0.99*sum(cs_in))

__device__ __forceinline__ u64 enc_pair(float s, int idx) {
  u32 u = __float_as_uint(s);
  u = (u & 0x80000000u) ? ~u : (u | 0x80000000u);   // order-preserving
  return ((u64)u << 32) | (u32)(~idx);              // ~idx: ties -> min idx
}
__device__ __forceinline__ float dec_score(u64 e) {
  u32 u = (u32)(e >> 32);
  u = (u & 0x80000000u) ? (u & 0x7fffffffu) : ~u;
  return __uint_as_float(u);
}
__device__ __forceinline__ int dec_idx(u64 e) { return (int)(~(u32)e); }
__device__ __forceinline__ unsigned short f2h(float f) {  // f32 -> fp16 RNE
  union { _Float16 h; unsigned short u; } v;
  v.h = (_Float16)f;
  return v.u;
}
// exact f32 chain (identical FMA order across screen/fixup uses)
__device__ __forceinline__ float exact_dot(const float* __restrict__ sx,
                                           const float* __restrict__ emb, int k) {
  const float4* e = (const float4*)(emb + (size_t)k * 64);
  float a = 0.f;
#pragma unroll
  for (int q = 0; q < 16; ++q) {
    float4 v = e[q];
    a = fmaf(sx[4 * q],     v.x, a);
    a = fmaf(sx[4 * q + 1], v.y, a);
    a = fmaf(sx[4 * q + 2], v.z, a);
    a = fmaf(sx[4 * q + 3], v.w, a);
  }
  return a;
}

// ---- fused prep: [0,512) eprep | [512,1032) init | [1032,1544) zprep -----
// eprep: en = 0.5*||e||^2 + emb -> fp16 16x16 B-frags; cnt=0
// init : out5 = 0.99*avg; solo block 1031: out4 = 0.99*cs AND nsum
// zprep: z_e -> fp16 16x16 A-frags; one 16-B cell per thread
__global__ __launch_bounds__(256) void k_prep(const float* __restrict__ emb,
                                              const float* __restrict__ cs_in,
                                              const float* __restrict__ avg_in,
                                              const float* __restrict__ z_e,
                                              float* __restrict__ en,
                                              unsigned char* __restrict__ efrag,
                                              unsigned char* __restrict__ zfrag,
                                              float* __restrict__ out4,
                                              float* __restrict__ out5,
                                              int* __restrict__ cnt,
                                              float* __restrict__ nsum) {
  __shared__ float warr[4];
  int bid = blockIdx.x;
  if (bid < 512) {                    // ---- eprep: 131072 float4s of emb
    int tid = bid * 256 + threadIdx.x;
    if (tid == 0) *cnt = 0;
    int k = tid >> 4, q = tid & 15;   // code k, channels 4q..4q+3
    float4 v = ((const float4*)emb)[tid];
    ushort4 hv;
    hv.x = f2h(v.x); hv.y = f2h(v.y); hv.z = f2h(v.z); hv.w = f2h(v.w);
    // tile=k>>4, col=k&15, frag=c>>5=q>>3, kib=(c>>3)&3=(q>>1)&3, half=q&1
    size_t off = (size_t)(k >> 4) * 2048 + (size_t)(q >> 3) * 1024
               + (size_t)((q >> 1) & 3) * 256 + (size_t)(k & 15) * 16
               + (size_t)(q & 1) * 8;
    *(ushort4*)(efrag + off) = hv;
    float s = v.x * v.x + v.y * v.y + v.z * v.z + v.w * v.w;
    s += __shfl_xor(s, 1, 16);
    s += __shfl_xor(s, 2, 16);
    s += __shfl_xor(s, 4, 16);
    s += __shfl_xor(s, 8, 16);
    if (q == 0) en[k] = 0.5f * s;
  } else if (bid < 1031) {            // ---- init avg: 131072 float4s
    int tid = (bid - 512) * 256 + threadIdx.x;
    if (tid < 131072) {
      float4 v = ((const float4*)avg_in)[tid];
      v.x *= DECAYF; v.y *= DECAYF; v.z *= DECAYF; v.w *= DECAYF;
      ((float4*)out5)[tid] = v;
    }
  } else if (bid == 1031) {           // ---- solo: cs scale + total sum
    int thr = threadIdx.x;
    float s = 0.f;
#pragma unroll
    for (int q = 0; q < 8; ++q) {
      int idx = q * 256 + thr;                 // 2048 float4s of cluster_size
      float4 v = ((const float4*)cs_in)[idx];
      v.x *= DECAYF; v.y *= DECAYF; v.z *= DECAYF; v.w *= DECAYF;
      ((float4*)out4)[idx] = v;
      s += v.x + v.y + v.z + v.w;              // already x0.99
    }
    s += __shfl_xor(s, 1, 64);
    s += __shfl_xor(s, 2, 64);
    s += __shfl_xor(s, 4, 64);
    s += __shfl_xor(s, 8, 64);
    s += __shfl_xor(s, 16, 64);
    s += __shfl_xor(s, 32, 64);
    if ((thr & 63) == 0) warr[thr >> 6] = s;
    __syncthreads();
    if (thr == 0) *nsum = warr[0] + warr[1] + warr[2] + warr[3];
  } else {                            // ---- zprep: 131072 threads (16-B cell each)
    int id = (bid - 1032) * 256 + threadIdx.x;
    int n = id & 16383, k = id >> 14;          // token n, 8-ch cell k (0..7)
    int b = n >> 10, hw = n & 1023;
    const float* zr = z_e + ((size_t)b << 16) + ((size_t)(k * 8) << 10) + hw;
    unsigned short u[8];
#pragma unroll
    for (int j = 0; j < 8; ++j) u[j] = f2h(zr[(size_t)j << 10]);
    // tile=n>>4, row=n&15, frag=k>>2, kib=k&3
    size_t off = (size_t)(n >> 4) * 2048 + (size_t)(k >> 2) * 1024
               + (size_t)(k & 3) * 256 + (size_t)(n & 15) * 16;
    *(ushort4*)(zfrag + off)     = make_ushort4(u[0], u[1], u[2], u[3]);
    *(ushort4*)(zfrag + off + 8) = make_ushort4(u[4], u[5], u[6], u[7]);
  }
}

// ---- MFMA argmin: 16x16x32 fp16; 2 token-tiles/wave; double-buffered LDS -
// grid 1024 = 128 token-groups x 8 K-slices (1024 codes = 64 tiles)
__global__ __launch_bounds__(256) void k_argmin_mfma(
    const unsigned char* __restrict__ zfrag,
    const unsigned char* __restrict__ efrag,
    const float* __restrict__ en, u64* __restrict__ best1,
    float* __restrict__ best2) {
  alignas(16) __shared__ unsigned char sbuf[2][8192];   // dbuf: 4 tiles each
  __shared__ float sen[1024];                           // 0.5*||e||^2 slice
  const int tb = blockIdx.x >> 3;            // token group (128 tokens)
  const int sl = blockIdx.x & 7;             // K-slice (1024 codes)
  const int wave = threadIdx.x >> 6, lane = threadIdx.x & 63;
  const int col = lane & 15, g4 = lane >> 4;
  const int token0 = tb * 128 + wave * 32;
  const int scb = sl << 10;

  // en slice -> LDS (1024 f32 = 256 float4)
  ((float4*)sen)[threadIdx.x] = ((const float4*)(en + scb))[threadIdx.x];

  // A fragments: 2 token-tiles x 2 K-frags, direct vector loads from zfrag
  f16x8 a[2][2];
  {
    const unsigned char* zb = zfrag + ((size_t)(tb * 8 + wave * 2)) * 2048
                            + (size_t)g4 * 256 + (size_t)col * 16;
    a[0][0] = *(const f16x8*)(zb);
    a[0][1] = *(const f16x8*)(zb + 1024);
    a[1][0] = *(const f16x8*)(zb + 2048);
    a[1][1] = *(const f16x8*)(zb + 3072);
  }
  float b1[8], b2[8];
#pragma unroll
  for (int r = 0; r < 8; ++r) { b1[r] = -3.0e38f; b2[r] = -3.0e38f; }

  const unsigned char* gbase0 = efrag + (size_t)scb * 128;   // 128 B/code
  auto stage = [&](int ib, int buf) {
    const unsigned char* g = gbase0 + (size_t)ib * 8192 + (size_t)wave * 2048;
#pragma unroll
    for (int it = 0; it < 2; ++it) {
      __builtin_amdgcn_global_load_lds(
          (const __attribute__((address_space(1))) u32*)(g + it * 1024 + lane * 16),
          (__attribute__((address_space(3))) u32*)(&sbuf[buf][wave * 2048 + it * 1024]),
          16, 0, 0);
    }
  };
  stage(0, 0);                                // prologue
  for (int ib = 0; ib < 16; ++ib) {
    __syncthreads();                          // drains vmcnt -> stage(ib) done
    if (ib < 15) stage(ib + 1, (ib + 1) & 1); // prefetch overlaps compute(ib)
    const unsigned char* sb0 = &sbuf[ib & 1][0];
#pragma unroll
    for (int ct = 0; ct < 4; ++ct) {
      const int t = ib * 4 + ct;              // 0..63 tile id in slice
      const float negen = -sen[t * 16 + col]; // this lane's code column
      f16x8 bf0 = *(const f16x8*)(sb0 + ct * 2048 + lane * 16);
      f16x8 bf1 = *(const f16x8*)(sb0 + ct * 2048 + 1024 + lane * 16);
      f32x4 acc0, acc1;
#pragma unroll
      for (int r = 0; r < 4; ++r) { acc0[r] = negen; acc1[r] = negen; }
      acc0 = __builtin_amdgcn_mfma_f32_16x16x32_f16(a[0][0], bf0, acc0, 0, 0, 0);
      acc0 = __builtin_amdgcn_mfma_f32_16x16x32_f16(a[0][1], bf1, acc0, 0, 0, 0);
      acc1 = __builtin_amdgcn_mfma_f32_16x16x32_f16(a[1][0], bf0, acc1, 0, 0, 0);
      acc1 = __builtin_amdgcn_mfma_f32_16x16x32_f16(a[1][1], bf1, acc1, 0, 0, 0);
      const u32 emb6 = (u32)(63 - t);         // tile idx in low 6 mantissa bits
#pragma unroll
      for (int r = 0; r < 4; ++r) {
        float f0 = __uint_as_float((__float_as_uint(acc0[r]) & 0xFFFFFFC0u) | emb6);
        b2[r] = __builtin_amdgcn_fmed3f(f0, b1[r], b2[r]);
        b1[r] = fmaxf(b1[r], f0);
        float f1 = __uint_as_float((__float_as_uint(acc1[r]) & 0xFFFFFFC0u) | emb6);
        b2[4 + r] = __builtin_amdgcn_fmed3f(f1, b1[4 + r], b2[4 + r]);
        b1[4 + r] = fmaxf(b1[4 + r], f1);
      }
    }
  }
  // reduce across the 16 code-columns (lanes within each 16-lane group)
  int mi[8];
#pragma unroll
  for (int r = 0; r < 8; ++r) mi[r] = col;
#pragma unroll
  for (int st = 1; st < 16; st <<= 1) {
#pragma unroll
    for (int r = 0; r < 8; ++r) {
      float ob1 = __shfl_xor(b1[r], st, 64);
      float ob2 = __shfl_xor(b2[r], st, 64);
      int omi = __shfl_xor(mi[r], st, 64);
      bool ogt = ob1 > b1[r];            // strict: equal -> quantized tie -> fixup
      b2[r] = fmaxf(fminf(b1[r], ob1), fmaxf(b2[r], ob2));
      mi[r] = ogt ? omi : mi[r];
      b1[r] = fmaxf(b1[r], ob1);
    }
  }
  if (col == 0) {   // lanes 0,16,32,48: 8 token-rows each; [sl][token] layout
#pragma unroll
    for (int r = 0; r < 8; ++r) {
      int tset = r >> 2, rr = r & 3;
      int token = token0 + tset * 16 + g4 * 4 + rr;   // C/D row map [m89]
      int t = 63 - (int)(__float_as_uint(b1[r]) & 63u);
      int gcode = scb + t * 16 + mi[r];
      best1[(size_t)sl * 16384 + token] = enc_pair(b1[r], gcode);
      best2[(size_t)sl * 16384 + token] = b2[r];
    }
  }
}

// ---- merge slices, pick top1, flag ambiguous tokens ---------------------
__global__ __launch_bounds__(256) void k_resolve(const u64* __restrict__ best1,
                                                 const float* __restrict__ best2,
                                                 int* __restrict__ idxa,
                                                 int* __restrict__ list,
                                                 int* __restrict__ cnt) {
  int n = blockIdx.x * 256 + threadIdx.x;   // 16384
  u64 e[8];
  float sp[8];
#pragma unroll
  for (int s = 0; s < 8; ++s) {
    e[s]  = best1[(size_t)s * 16384 + n];
    sp[s] = best2[(size_t)s * 16384 + n];
  }
  u64 top = e[0];
#pragma unroll
  for (int s = 1; s < 8; ++s) top = e[s] > top ? e[s] : top;
  float second = -3.0e38f;
#pragma unroll
  for (int s = 0; s < 8; ++s) second = fmaxf(second, sp[s]);
#pragma unroll
  for (int s = 0; s < 8; ++s)
    if (e[s] != top) second = fmaxf(second, dec_score(e[s]));
  idxa[n] = dec_idx(top);
  if (dec_score(top) - second < TAU) {
    int p = atomicAdd(cnt, 1);
    list[p] = n;
  }
}

// ---- candidate-based exact fp32 fixup: one block per flagged token ------
// Candidates: per-slice best with screened >= theta; slices whose 2nd-best
// >= theta get a full 1024-code exact rescan. theta = top - TAU.
// Rigor: |exact - screened| <= eps, TAU >= 2*eps  =>  true argmin in set.
// Writes idxa directly (block owns the token).
__global__ __launch_bounds__(256) void k_fixup(const float* __restrict__ z_e,
                                               const float* __restrict__ emb,
                                               const float* __restrict__ en,
                                               const u64* __restrict__ best1,
                                               const float* __restrict__ best2,
                                               const int* __restrict__ list,
                                               const int* __restrict__ cnt,
                                               int* __restrict__ idxa) {
  __shared__ float sx[64];
  __shared__ u64 esh[8];
  __shared__ float b2sh[8];
  __shared__ int cand[8];
  __shared__ int fsl[8];
  __shared__ int ncand, nfsl;
  __shared__ u64 red;
  int count = *cnt;
  for (int i = blockIdx.x; i < count; i += gridDim.x) {
    int n = list[i];
    __syncthreads();                       // protect prev-iter LDS
    if (threadIdx.x == 0) { ncand = 0; nfsl = 0; red = 0ull; }
    if (threadIdx.x < 8) {
      esh[threadIdx.x]  = best1[(size_t)threadIdx.x * 16384 + n];
      b2sh[threadIdx.x] = best2[(size_t)threadIdx.x * 16384 + n];
    }
    if (threadIdx.x < 64) {
      sx[threadIdx.x] = z_e[((size_t)(n >> 10) << 16)
                            + ((size_t)threadIdx.x << 10) + (n & 1023)];
    }
    __syncthreads();
    u64 top = esh[0];
#pragma unroll
    for (int s = 1; s < 8; ++s) top = esh[s] > top ? esh[s] : top;
    float theta = dec_score(top) - TAU;
    if (threadIdx.x < 8) {
      int s = threadIdx.x;
      if (dec_score(esh[s]) >= theta) {
        int p = atomicAdd(&ncand, 1);
        cand[p] = dec_idx(esh[s]);
      }
      if (b2sh[s] >= theta) {
        int p = atomicAdd(&nfsl, 1);
        fsl[p] = s;
      }
    }
    __syncthreads();
    u64 myb = 0ull;
    if (threadIdx.x < ncand) {             // phase 1: <=8 candidate codes
      int k = cand[threadIdx.x];
      float a = exact_dot(sx, emb, k) - en[k];
      myb = enc_pair(a, k);
    }
    int nf = nfsl;
    for (int f = 0; f < nf; ++f) {         // phase 2: rare full-slice rescan
      int s = fsl[f];
      int k0 = (s << 10) + threadIdx.x;    // 4 codes: +0,+256,+512,+768
      float a0 = exact_dot(sx, emb, k0)       - en[k0];
      float a1 = exact_dot(sx, emb, k0 + 256) - en[k0 + 256];
      float a2 = exact_dot(sx, emb, k0 + 512) - en[k0 + 512];
      float a3 = exact_dot(sx, emb, k0 + 768) - en[k0 + 768];
      u64 m0 = enc_pair(a0, k0),       m1 = enc_pair(a1, k0 + 256);
      u64 m2 = enc_pair(a2, k0 + 512), m3 = enc_pair(a3, k0 + 768);
      u64 ma = m0 > m1 ? m0 : m1, mb = m2 > m3 ? m2 : m3;
      u64 mm = ma > mb ? ma : mb;
      myb = mm > myb ? mm : myb;
    }
    if (myb) atomicMax(&red, myb);
    __syncthreads();
    if (threadIdx.x == 0) idxa[n] = dec_idx(red);
  }
}

// ---- scatter EMA stats (lane = channel -> coalesced atomics) -------------
__global__ __launch_bounds__(256) void k_scatter(const float* __restrict__ z_e,
                                                 const int* __restrict__ idxa,
                                                 float* __restrict__ out4,
                                                 float* __restrict__ out5) {
  int tid = blockIdx.x * 256 + threadIdx.x;   // 1M = 16384 tokens x 64 ch
  int n = tid >> 6, c = tid & 63;
  int idx = idxa[n];
  int b = n >> 10, hw = n & 1023;
  float x = z_e[((size_t)b << 16) + ((size_t)c << 10) + hw];
  atomicAdd(out5 + (size_t)idx * 64 + c, OMDF * x);
  if (c == 0) atomicAdd(out4 + idx, OMDF);
}

// ---- gather z_q / z_q_st / indices --------------------------------------
__global__ __launch_bounds__(256) void k_gather(const float* __restrict__ z_e,
                                                const float* __restrict__ emb,
                                                const int* __restrict__ idxa,
                                                float* __restrict__ out0,
                                                float* __restrict__ out1,
                                                float* __restrict__ out2) {
  int tid = blockIdx.x * 256 + threadIdx.x;   // 262144 = 16 b x 64 c x 256 hw4
  int hw4 = tid & 255;
  int c   = (tid >> 8) & 63;
  int b   = tid >> 14;
  int n0  = (b << 10) + (hw4 << 2);
  size_t off = ((size_t)b << 16) + ((size_t)c << 10) + ((size_t)hw4 << 2);
  float4 z = *(const float4*)(z_e + off);
  int i0 = idxa[n0], i1 = idxa[n0 + 1], i2 = idxa[n0 + 2], i3 = idxa[n0 + 3];
  float4 q;
  q.x = emb[(size_t)i0 * 64 + c];
  q.y = emb[(size_t)i1 * 64 + c];
  q.z = emb[(size_t)i2 * 64 + c];
  q.w = emb[(size_t)i3 * 64 + c];
  float4 st;
  st.x = z.x + (q.x - z.x);
  st.y = z.y + (q.y - z.y);
  st.z = z.z + (q.z - z.z);
  st.w = z.w + (q.w - z.w);
  *(float4*)(out2 + off) = q;
  *(float4*)(out0 + off) = st;
  if (c == 0) {
    float4 f = make_float4((float)i0, (float)i1, (float)i2, (float)i3);
    *(float4*)(out1 + n0) = f;
  }
}

// ---- new_embedding = new_embedding_avg / cs -----------------------------
__global__ __launch_bounds__(256) void k_final(const float* __restrict__ out4,
                                               const float* __restrict__ out5,
                                               const float* __restrict__ nsum,
                                               float* __restrict__ out3) {
  int tid = blockIdx.x * 256 + threadIdx.x;
  int k = tid >> 4;
  double nn  = (double)*nsum + 163.84;
  double ncs = (double)out4[k];
  double cs  = (ncs + 1e-5) / (nn + 8192.0 * 1e-5) * nn;
  float inv  = (float)(1.0 / cs);
  float4 v = ((const float4*)out5)[tid];
  v.x *= inv; v.y *= inv; v.z *= inv; v.w *= inv;
  ((float4*)out3)[tid] = v;
}

extern "C" void kernel_launch(void* const* d_in, const int* in_sizes, int n_in,
                              void* d_out, int out_size, void* d_ws, size_t ws_size,
                              hipStream_t stream) {
  const float* z_e    = (const float*)d_in[0];
  const float* emb    = (const float*)d_in[1];
  const float* cs_in  = (const float*)d_in[2];
  const float* avg_in = (const float*)d_in[3];

  float* out  = (float*)d_out;
  float* out0 = out;                    // z_q_st        1048576
  float* out1 = out0 + 1048576;         // indices(f32)  16384
  float* out2 = out1 + 16384;           // z_q           1048576
  float* out3 = out2 + 1048576;         // new_embedding 524288
  float* out4 = out3 + 524288;          // new_cluster   8192
  float* out5 = out4 + 8192;            // new_emb_avg   524288

  char* ws = (char*)d_ws;
  float* en            = (float*)(ws + EN_OFF);
  unsigned char* efrag = (unsigned char*)(ws + EFRAG_OFF);
  u64* best1           = (u64*)(ws + BEST1_OFF);
  float* best2         = (float*)(ws + BEST2_OFF);
  int* idxa            = (int*)(ws + IDX_OFF);
  int* list            = (int*)(ws + LIST_OFF);
  int* cnt             = (int*)(ws + CNT_OFF);
  float* nsum          = (float*)(ws + CNT_OFF + 4);
  unsigned char* zfrag = (unsigned char*)out0;   // 2 MB scratch in out0 region

  k_prep       <<<1544, 256, 0, stream>>>(emb, cs_in, avg_in, z_e, en, efrag,
                                          zfrag, out4, out5, cnt, nsum);
  k_argmin_mfma<<<1024, 256, 0, stream>>>(zfrag, efrag, en, best1, best2);
  k_resolve    <<<64,   256, 0, stream>>>(best1, best2, idxa, list, cnt);
  k_fixup      <<<1024, 256, 0, stream>>>(z_e, emb, en, best1, best2, list, cnt, idxa);
  k_scatter    <<<4096, 256, 0, stream>>>(z_e, idxa, out4, out5);
  k_gather     <<<1024, 256, 0, stream>>>(z_e, emb, idxa, out0, out1, out2);
  k_final      <<<512,  256, 0, stream>>>(out4, out5, nsum, out3);
}

// Round 8
// 147.650 us; speedup vs baseline: 1.2346x; 1.0085x over previous
//
#include <hip/hip_runtime.h>

// Problem: B=16,C=64,H=32,W=32 -> N=16384 tokens; K=8192 codes.
#define DECAYF 0.99f
#define OMDF   0.01f
#define TAU    3.5e-2f   // fp16 screen: ~9-sigma pairwise (sigma~3.8e-3); candidate fixup exact f32

typedef unsigned int u32;
typedef unsigned long long u64;
typedef __attribute__((ext_vector_type(8))) _Float16 f16x8;  // 8 fp16 (4 VGPRs)
typedef __attribute__((ext_vector_type(4))) float f32x4;     // MFMA 16x16 acc

// ws layout (bytes). High-water = 3702792.
// zfrag (2 MB, fp16 z_e in 16x16 A-frag order) lives in the out0 output
// region: written by k_prep, read by k_argmin, overwritten by k_gather.
// IDX/LIST overlay EFRAG (efrag dead after k_argmin; stream-ordered).
// efrag: 512 tiles x 2048 B. Tile (16 codes): [frag0 1KB][frag1 1KB], each
// laid out lane*16 with cell (kblk=lane>>4, code=lane&15) = 8 contiguous ch.
#define EN_OFF     0              // en[8192] f32: 0.5*||e||^2
#define EFRAG_OFF  32768          // 1 MB frag-ordered fp16 emb (128 B/code)
#define IDX_OFF    32768          // i32 [16384] final indices       (overlay)
#define LIST_OFF   98304          // i32 [16384] ambiguous list      (overlay)
#define BEST1_OFF  2129920        // u64 [8][16384] per-(slice,token) best (enc)
#define BEST2_OFF  3178496        // f32 [8][16384] per-(slice,token) 2nd-best
#define CNT_OFF    3702784        // i32 count ; +4: f32 nsum (0.99*sum(cs_in))

__device__ __forceinline__ u64 enc_pair(float s, int idx) {
  u32 u = __float_as_uint(s);
  u = (u & 0x80000000u) ? ~u : (u | 0x80000000u);   // order-preserving
  return ((u64)u << 32) | (u32)(~idx);              // ~idx: ties -> min idx
}
__device__ __forceinline__ float dec_score(u64 e) {
  u32 u = (u32)(e >> 32);
  u = (u & 0x80000000u) ? (u & 0x7fffffffu) : ~u;
  return __uint_as_float(u);
}
__device__ __forceinline__ int dec_idx(u64 e) { return (int)(~(u32)e); }
__device__ __forceinline__ unsigned short f2h(float f) {  // f32 -> fp16 RNE
  union { _Float16 h; unsigned short u; } v;
  v.h = (_Float16)f;
  return v.u;
}
// exact f32 chain (identical FMA order across screen/fixup uses)
__device__ __forceinline__ float exact_dot(const float* __restrict__ sx,
                                           const float* __restrict__ emb, int k) {
  const float4* e = (const float4*)(emb + (size_t)k * 64);
  float a = 0.f;
#pragma unroll
  for (int q = 0; q < 16; ++q) {
    float4 v = e[q];
    a = fmaf(sx[4 * q],     v.x, a);
    a = fmaf(sx[4 * q + 1], v.y, a);
    a = fmaf(sx[4 * q + 2], v.z, a);
    a = fmaf(sx[4 * q + 3], v.w, a);
  }
  return a;
}

// ---- fused prep: [0,512) eprep | [512,1032) init | [1032,1544) zprep -----
// eprep: en = 0.5*||e||^2 + emb -> fp16 16x16 B-frags; cnt=0
// init : out5 = 0.99*avg; solo block 1031: out4 = 0.99*cs AND nsum
// zprep: z_e -> fp16 16x16 A-frags; one 16-B cell per thread
__global__ __launch_bounds__(256) void k_prep(const float* __restrict__ emb,
                                              const float* __restrict__ cs_in,
                                              const float* __restrict__ avg_in,
                                              const float* __restrict__ z_e,
                                              float* __restrict__ en,
                                              unsigned char* __restrict__ efrag,
                                              unsigned char* __restrict__ zfrag,
                                              float* __restrict__ out4,
                                              float* __restrict__ out5,
                                              int* __restrict__ cnt,
                                              float* __restrict__ nsum) {
  __shared__ float warr[4];
  int bid = blockIdx.x;
  if (bid < 512) {                    // ---- eprep: 131072 float4s of emb
    int tid = bid * 256 + threadIdx.x;
    if (tid == 0) *cnt = 0;
    int k = tid >> 4, q = tid & 15;   // code k, channels 4q..4q+3
    float4 v = ((const float4*)emb)[tid];
    ushort4 hv;
    hv.x = f2h(v.x); hv.y = f2h(v.y); hv.z = f2h(v.z); hv.w = f2h(v.w);
    // tile=k>>4, col=k&15, frag=q>>3, kib=(q>>1)&3, half=q&1
    size_t off = (size_t)(k >> 4) * 2048 + (size_t)(q >> 3) * 1024
               + (size_t)((q >> 1) & 3) * 256 + (size_t)(k & 15) * 16
               + (size_t)(q & 1) * 8;
    *(ushort4*)(efrag + off) = hv;
    float s = v.x * v.x + v.y * v.y + v.z * v.z + v.w * v.w;
    s += __shfl_xor(s, 1, 16);
    s += __shfl_xor(s, 2, 16);
    s += __shfl_xor(s, 4, 16);
    s += __shfl_xor(s, 8, 16);
    if (q == 0) en[k] = 0.5f * s;
  } else if (bid < 1031) {            // ---- init avg: 131072 float4s
    int tid = (bid - 512) * 256 + threadIdx.x;
    if (tid < 131072) {
      float4 v = ((const float4*)avg_in)[tid];
      v.x *= DECAYF; v.y *= DECAYF; v.z *= DECAYF; v.w *= DECAYF;
      ((float4*)out5)[tid] = v;
    }
  } else if (bid == 1031) {           // ---- solo: cs scale + total sum
    int thr = threadIdx.x;
    float s = 0.f;
#pragma unroll
    for (int q = 0; q < 8; ++q) {
      int idx = q * 256 + thr;                 // 2048 float4s of cluster_size
      float4 v = ((const float4*)cs_in)[idx];
      v.x *= DECAYF; v.y *= DECAYF; v.z *= DECAYF; v.w *= DECAYF;
      ((float4*)out4)[idx] = v;
      s += v.x + v.y + v.z + v.w;              // already x0.99
    }
    s += __shfl_xor(s, 1, 64);
    s += __shfl_xor(s, 2, 64);
    s += __shfl_xor(s, 4, 64);
    s += __shfl_xor(s, 8, 64);
    s += __shfl_xor(s, 16, 64);
    s += __shfl_xor(s, 32, 64);
    if ((thr & 63) == 0) warr[thr >> 6] = s;
    __syncthreads();
    if (thr == 0) *nsum = warr[0] + warr[1] + warr[2] + warr[3];
  } else {                            // ---- zprep: 131072 threads (16-B cell each)
    int id = (bid - 1032) * 256 + threadIdx.x;
    int n = id & 16383, k = id >> 14;          // token n, 8-ch cell k (0..7)
    int b = n >> 10, hw = n & 1023;
    const float* zr = z_e + ((size_t)b << 16) + ((size_t)(k * 8) << 10) + hw;
    unsigned short u[8];
#pragma unroll
    for (int j = 0; j < 8; ++j) u[j] = f2h(zr[(size_t)j << 10]);
    // tile=n>>4, row=n&15, frag=k>>2, kib=k&3
    size_t off = (size_t)(n >> 4) * 2048 + (size_t)(k >> 2) * 1024
               + (size_t)(k & 3) * 256 + (size_t)(n & 15) * 16;
    *(ushort4*)(zfrag + off)     = make_ushort4(u[0], u[1], u[2], u[3]);
    *(ushort4*)(zfrag + off + 8) = make_ushort4(u[4], u[5], u[6], u[7]);
  }
}

// ---- MFMA argmin: 16x16x32 fp16; 1 token-tile/wave; double-buffered LDS --
// grid 2048 = 256 token-groups (64 tokens) x 8 K-slices -> ~7 blk/CU resident
__global__ __launch_bounds__(256) void k_argmin_mfma(
    const unsigned char* __restrict__ zfrag,
    const unsigned char* __restrict__ efrag,
    const float* __restrict__ en, u64* __restrict__ best1,
    float* __restrict__ best2) {
  alignas(16) __shared__ unsigned char sbuf[2][8192];   // dbuf: 4 tiles each
  __shared__ float sen[1024];                           // 0.5*||e||^2 slice
  const int tb = blockIdx.x >> 3;            // token group (64 tokens)
  const int sl = blockIdx.x & 7;             // K-slice (1024 codes)
  const int wave = threadIdx.x >> 6, lane = threadIdx.x & 63;
  const int col = lane & 15, g4 = lane >> 4;
  const int token0 = tb * 64 + wave * 16;
  const int scb = sl << 10;

  // en slice -> LDS (1024 f32 = 256 float4)
  ((float4*)sen)[threadIdx.x] = ((const float4*)(en + scb))[threadIdx.x];

  // A fragments: 1 token-tile x 2 K-frags, direct vector loads from zfrag
  f16x8 a0, a1;
  {
    const unsigned char* zb = zfrag + ((size_t)(tb * 4 + wave)) * 2048
                            + (size_t)g4 * 256 + (size_t)col * 16;
    a0 = *(const f16x8*)(zb);
    a1 = *(const f16x8*)(zb + 1024);
  }
  float b1[4], b2[4];
#pragma unroll
  for (int r = 0; r < 4; ++r) { b1[r] = -3.0e38f; b2[r] = -3.0e38f; }

  const unsigned char* gbase0 = efrag + (size_t)scb * 128;   // 128 B/code
  auto stage = [&](int ib, int buf) {
    const unsigned char* g = gbase0 + (size_t)ib * 8192 + (size_t)wave * 2048;
#pragma unroll
    for (int it = 0; it < 2; ++it) {
      __builtin_amdgcn_global_load_lds(
          (const __attribute__((address_space(1))) u32*)(g + it * 1024 + lane * 16),
          (__attribute__((address_space(3))) u32*)(&sbuf[buf][wave * 2048 + it * 1024]),
          16, 0, 0);
    }
  };
  stage(0, 0);                                // prologue
  for (int ib = 0; ib < 16; ++ib) {
    __syncthreads();                          // drains vmcnt -> stage(ib) done
    if (ib < 15) stage(ib + 1, (ib + 1) & 1); // prefetch overlaps compute(ib)
    const unsigned char* sb0 = &sbuf[ib & 1][0];
#pragma unroll
    for (int ct = 0; ct < 4; ++ct) {
      const int t = ib * 4 + ct;              // 0..63 tile id in slice
      const float negen = -sen[t * 16 + col]; // this lane's code column
      f16x8 bf0 = *(const f16x8*)(sb0 + ct * 2048 + lane * 16);
      f16x8 bf1 = *(const f16x8*)(sb0 + ct * 2048 + 1024 + lane * 16);
      f32x4 acc;
#pragma unroll
      for (int r = 0; r < 4; ++r) acc[r] = negen;   // fold -0.5||e||^2 into C
      acc = __builtin_amdgcn_mfma_f32_16x16x32_f16(a0, bf0, acc, 0, 0, 0);
      acc = __builtin_amdgcn_mfma_f32_16x16x32_f16(a1, bf1, acc, 0, 0, 0);
      const u32 emb6 = (u32)(63 - t);         // tile idx in low 6 mantissa bits
#pragma unroll
      for (int r = 0; r < 4; ++r) {
        float f0 = __uint_as_float((__float_as_uint(acc[r]) & 0xFFFFFFC0u) | emb6);
        b2[r] = __builtin_amdgcn_fmed3f(f0, b1[r], b2[r]);
        b1[r] = fmaxf(b1[r], f0);
      }
    }
  }
  // reduce across the 16 code-columns (lanes within each 16-lane group)
  int mi[4];
#pragma unroll
  for (int r = 0; r < 4; ++r) mi[r] = col;
#pragma unroll
  for (int st = 1; st < 16; st <<= 1) {
#pragma unroll
    for (int r = 0; r < 4; ++r) {
      float ob1 = __shfl_xor(b1[r], st, 64);
      float ob2 = __shfl_xor(b2[r], st, 64);
      int omi = __shfl_xor(mi[r], st, 64);
      bool ogt = ob1 > b1[r];            // strict: equal -> quantized tie -> fixup
      b2[r] = fmaxf(fminf(b1[r], ob1), fmaxf(b2[r], ob2));
      mi[r] = ogt ? omi : mi[r];
      b1[r] = fmaxf(b1[r], ob1);
    }
  }
  if (col == 0) {   // lanes 0,16,32,48: 4 token-rows each; [sl][token] layout
#pragma unroll
    for (int r = 0; r < 4; ++r) {
      int token = token0 + g4 * 4 + r;        // C/D row map [m89]
      int t = 63 - (int)(__float_as_uint(b1[r]) & 63u);
      int gcode = scb + t * 16 + mi[r];
      best1[(size_t)sl * 16384 + token] = enc_pair(b1[r], gcode);
      best2[(size_t)sl * 16384 + token] = b2[r];
    }
  }
}

// ---- merge slices, pick top1, flag ambiguous tokens ---------------------
__global__ __launch_bounds__(256) void k_resolve(const u64* __restrict__ best1,
                                                 const float* __restrict__ best2,
                                                 int* __restrict__ idxa,
                                                 int* __restrict__ list,
                                                 int* __restrict__ cnt) {
  int n = blockIdx.x * 256 + threadIdx.x;   // 16384
  u64 e[8];
  float sp[8];
#pragma unroll
  for (int s = 0; s < 8; ++s) {
    e[s]  = best1[(size_t)s * 16384 + n];
    sp[s] = best2[(size_t)s * 16384 + n];
  }
  u64 top = e[0];
#pragma unroll
  for (int s = 1; s < 8; ++s) top = e[s] > top ? e[s] : top;
  float second = -3.0e38f;
#pragma unroll
  for (int s = 0; s < 8; ++s) second = fmaxf(second, sp[s]);
#pragma unroll
  for (int s = 0; s < 8; ++s)
    if (e[s] != top) second = fmaxf(second, dec_score(e[s]));
  idxa[n] = dec_idx(top);
  if (dec_score(top) - second < TAU) {
    int p = atomicAdd(cnt, 1);
    list[p] = n;
  }
}

// ---- candidate-based exact fp32 fixup: one block per flagged token ------
// Candidates: per-slice best with screened >= theta; slices whose 2nd-best
// >= theta get a full 1024-code exact rescan. theta = top - TAU.
// Rigor: |exact - screened| <= eps, TAU >= 2*eps  =>  true argmin in set.
// Writes idxa directly (block owns the token).
__global__ __launch_bounds__(256) void k_fixup(const float* __restrict__ z_e,
                                               const float* __restrict__ emb,
                                               const float* __restrict__ en,
                                               const u64* __restrict__ best1,
                                               const float* __restrict__ best2,
                                               const int* __restrict__ list,
                                               const int* __restrict__ cnt,
                                               int* __restrict__ idxa) {
  __shared__ float sx[64];
  __shared__ u64 esh[8];
  __shared__ float b2sh[8];
  __shared__ int cand[8];
  __shared__ int fsl[8];
  __shared__ int ncand, nfsl;
  __shared__ u64 red;
  int count = *cnt;
  for (int i = blockIdx.x; i < count; i += gridDim.x) {
    int n = list[i];
    __syncthreads();                       // protect prev-iter LDS
    if (threadIdx.x == 0) { ncand = 0; nfsl = 0; red = 0ull; }
    if (threadIdx.x < 8) {
      esh[threadIdx.x]  = best1[(size_t)threadIdx.x * 16384 + n];
      b2sh[threadIdx.x] = best2[(size_t)threadIdx.x * 16384 + n];
    }
    if (threadIdx.x < 64) {
      sx[threadIdx.x] = z_e[((size_t)(n >> 10) << 16)
                            + ((size_t)threadIdx.x << 10) + (n & 1023)];
    }
    __syncthreads();
    u64 top = esh[0];
#pragma unroll
    for (int s = 1; s < 8; ++s) top = esh[s] > top ? esh[s] : top;
    float theta = dec_score(top) - TAU;
    if (threadIdx.x < 8) {
      int s = threadIdx.x;
      if (dec_score(esh[s]) >= theta) {
        int p = atomicAdd(&ncand, 1);
        cand[p] = dec_idx(esh[s]);
      }
      if (b2sh[s] >= theta) {
        int p = atomicAdd(&nfsl, 1);
        fsl[p] = s;
      }
    }
    __syncthreads();
    u64 myb = 0ull;
    if (threadIdx.x < ncand) {             // phase 1: <=8 candidate codes
      int k = cand[threadIdx.x];
      float a = exact_dot(sx, emb, k) - en[k];
      myb = enc_pair(a, k);
    }
    int nf = nfsl;
    for (int f = 0; f < nf; ++f) {         // phase 2: rare full-slice rescan
      int s = fsl[f];
      int k0 = (s << 10) + threadIdx.x;    // 4 codes: +0,+256,+512,+768
      float a0 = exact_dot(sx, emb, k0)       - en[k0];
      float a1 = exact_dot(sx, emb, k0 + 256) - en[k0 + 256];
      float a2 = exact_dot(sx, emb, k0 + 512) - en[k0 + 512];
      float a3 = exact_dot(sx, emb, k0 + 768) - en[k0 + 768];
      u64 m0 = enc_pair(a0, k0),       m1 = enc_pair(a1, k0 + 256);
      u64 m2 = enc_pair(a2, k0 + 512), m3 = enc_pair(a3, k0 + 768);
      u64 ma = m0 > m1 ? m0 : m1, mb = m2 > m3 ? m2 : m3;
      u64 mm = ma > mb ? ma : mb;
      myb = mm > myb ? mm : myb;
    }
    if (myb) atomicMax(&red, myb);
    __syncthreads();
    if (threadIdx.x == 0) idxa[n] = dec_idx(red);
  }
}

// ---- scatter EMA stats (lane = channel -> coalesced atomics) -------------
__global__ __launch_bounds__(256) void k_scatter(const float* __restrict__ z_e,
                                                 const int* __restrict__ idxa,
                                                 float* __restrict__ out4,
                                                 float* __restrict__ out5) {
  int tid = blockIdx.x * 256 + threadIdx.x;   // 1M = 16384 tokens x 64 ch
  int n = tid >> 6, c = tid & 63;
  int idx = idxa[n];
  int b = n >> 10, hw = n & 1023;
  float x = z_e[((size_t)b << 16) + ((size_t)c << 10) + hw];
  atomicAdd(out5 + (size_t)idx * 64 + c, OMDF * x);
  if (c == 0) atomicAdd(out4 + idx, OMDF);
}

// ---- gather z_q / z_q_st / indices --------------------------------------
__global__ __launch_bounds__(256) void k_gather(const float* __restrict__ z_e,
                                                const float* __restrict__ emb,
                                                const int* __restrict__ idxa,
                                                float* __restrict__ out0,
                                                float* __restrict__ out1,
                                                float* __restrict__ out2) {
  int tid = blockIdx.x * 256 + threadIdx.x;   // 262144 = 16 b x 64 c x 256 hw4
  int hw4 = tid & 255;
  int c   = (tid >> 8) & 63;
  int b   = tid >> 14;
  int n0  = (b << 10) + (hw4 << 2);
  size_t off = ((size_t)b << 16) + ((size_t)c << 10) + ((size_t)hw4 << 2);
  float4 z = *(const float4*)(z_e + off);
  int i0 = idxa[n0], i1 = idxa[n0 + 1], i2 = idxa[n0 + 2], i3 = idxa[n0 + 3];
  float4 q;
  q.x = emb[(size_t)i0 * 64 + c];
  q.y = emb[(size_t)i1 * 64 + c];
  q.z = emb[(size_t)i2 * 64 + c];
  q.w = emb[(size_t)i3 * 64 + c];
  float4 st;
  st.x = z.x + (q.x - z.x);
  st.y = z.y + (q.y - z.y);
  st.z = z.z + (q.z - z.z);
  st.w = z.w + (q.w - z.w);
  *(float4*)(out2 + off) = q;
  *(float4*)(out0 + off) = st;
  if (c == 0) {
    float4 f = make_float4((float)i0, (float)i1, (float)i2, (float)i3);
    *(float4*)(out1 + n0) = f;
  }
}

// ---- new_embedding = new_embedding_avg / cs -----------------------------
__global__ __launch_bounds__(256) void k_final(const float* __restrict__ out4,
                                               const float* __restrict__ out5,
                                               const float* __restrict__ nsum,
                                               float* __restrict__ out3) {
  int tid = blockIdx.x * 256 + threadIdx.x;
  int k = tid >> 4;
  double nn  = (double)*nsum + 163.84;
  double ncs = (double)out4[k];
  double cs  = (ncs + 1e-5) / (nn + 8192.0 * 1e-5) * nn;
  float inv  = (float)(1.0 / cs);
  float4 v = ((const float4*)out5)[tid];
  v.x *= inv; v.y *= inv; v.z *= inv; v.w *= inv;
  ((float4*)out3)[tid] = v;
}

extern "C" void kernel_launch(void* const* d_in, const int* in_sizes, int n_in,
                              void* d_out, int out_size, void* d_ws, size_t ws_size,
                              hipStream_t stream) {
  const float* z_e    = (const float*)d_in[0];
  const float* emb    = (const float*)d_in[1];
  const float* cs_in  = (const float*)d_in[2];
  const float* avg_in = (const float*)d_in[3];

  float* out  = (float*)d_out;
  float* out0 = out;                    // z_q_st        1048576
  float* out1 = out0 + 1048576;         // indices(f32)  16384
  float* out2 = out1 + 16384;           // z_q           1048576
  float* out3 = out2 + 1048576;         // new_embedding 524288
  float* out4 = out3 + 524288;          // new_cluster   8192
  float* out5 = out4 + 8192;            // new_emb_avg   524288

  char* ws = (char*)d_ws;
  float* en            = (float*)(ws + EN_OFF);
  unsigned char* efrag = (unsigned char*)(ws + EFRAG_OFF);
  u64* best1           = (u64*)(ws + BEST1_OFF);
  float* best2         = (float*)(ws + BEST2_OFF);
  int* idxa            = (int*)(ws + IDX_OFF);
  int* list            = (int*)(ws + LIST_OFF);
  int* cnt             = (int*)(ws + CNT_OFF);
  float* nsum          = (float*)(ws + CNT_OFF + 4);
  unsigned char* zfrag = (unsigned char*)out0;   // 2 MB scratch in out0 region

  k_prep       <<<1544, 256, 0, stream>>>(emb, cs_in, avg_in, z_e, en, efrag,
                                          zfrag, out4, out5, cnt, nsum);
  k_argmin_mfma<<<2048, 256, 0, stream>>>(zfrag, efrag, en, best1, best2);
  k_resolve    <<<64,   256, 0, stream>>>(best1, best2, idxa, list, cnt);
  k_fixup      <<<1024, 256, 0, stream>>>(z_e, emb, en, best1, best2, list, cnt, idxa);
  k_scatter    <<<4096, 256, 0, stream>>>(z_e, idxa, out4, out5);
  k_gather     <<<1024, 256, 0, stream>>>(z_e, emb, idxa, out0, out1, out2);
  k_final      <<<512,  256, 0, stream>>>(out4, out5, nsum, out3);
}